// Round 5
// baseline (10276.188 us; speedup 1.0000x reference)
//
#include <hip/hip_runtime.h>

// ---------------------------------------------------------------------------
// 2-layer GRU (B=64,T=1024,D=256,H=512) + dense head, persistent-RNN style.
// v6: epoch-in-data exchange (v5 protocol) made SPILL-PROOF.
//   - h exchanged as u32 (step_tag<<16 | f16bits); consumers poll the data
//     (load + tag-validate + bounded retry). No producer drain, no flags, no
//     global barrier on the h recurrence. 2-deep slots safe by skew argument.
//   - EVERY exchange load group is ONE self-contained asm block: all loads +
//     s_waitcnt vmcnt(0) inside, "=&v" early-clobber outputs, immediate
//     offsets off one per-lane base. The compiler can never spill between
//     issue and wait (v5's crash mechanism: spilled pending-load dest regs).
//   - Self/peer store->load races are caught by tags (retry), watchdog'd.
//   - y0 handoff: lagged flag (published after a vmcnt-clean point +
//     __syncthreads), y loads issued only AFTER flag observed. 3 slots in
//     out-head (2) + c0 first half (1); c0 written in epilogue after L1
//     progress >= 1022. All spins clock64-watchdog'd + dead-latch: hang-proof.
// ---------------------------------------------------------------------------

#define T_STEPS 1024
#define NWG_L0  32
#define NWG_TOT 64

typedef _Float16 f16x8 __attribute__((ext_vector_type(8)));
typedef float    f32x4 __attribute__((ext_vector_type(4)));

// ws layout (bytes)
#define H0T_OFF   0u         // 2 slots x [64][512] u32 = 262144
#define H1T_OFF   262144u    // 2 slots x [64][512] u32 = 262144
#define YFLAG_OFF 524288u    // 32 x 64B
#define PROG_OFF  526336u    // 32 x 64B
#define WS_NEED   528384u
#define FST       16         // flag stride in u32 (64 B)

#define BUD_SPIN (1ull << 19)   // ~220us per spin, then dead-latch
#define BUD_EPI  (1ull << 22)

__device__ __forceinline__ float sigm_f(float x) { return 1.0f / (1.0f + __expf(-x)); }
__device__ __forceinline__ float tanh_f(float x) { return 2.0f / (1.0f + __expf(-2.0f * x)) - 1.0f; }

__device__ __forceinline__ f32x4 mfma16(f16x8 a, f16x8 b, f32x4 c) {
    return __builtin_amdgcn_mfma_f32_16x16x32_f16(a, b, c, 0, 0, 0);
}

__device__ __forceinline__ f16x8 pack8(const float* __restrict__ src, int stride) {
    f16x8 r;
#pragma unroll
    for (int j = 0; j < 8; ++j) r[j] = (_Float16)src[j * stride];
    return r;
}

// ---- self-contained load blocks (issue + wait INSIDE one asm) ----
// 32x dwordx4 (16 tagged-h frags) + 1 dword (flag/license) + vmcnt(0).
#define LDH33(W, PV, HB, PP) \
  asm volatile( \
    "global_load_dwordx4 %0, %33, off sc1\n\t" \
    "global_load_dwordx4 %1, %33, off offset:16 sc1\n\t" \
    "global_load_dwordx4 %2, %33, off offset:128 sc1\n\t" \
    "global_load_dwordx4 %3, %33, off offset:144 sc1\n\t" \
    "global_load_dwordx4 %4, %33, off offset:256 sc1\n\t" \
    "global_load_dwordx4 %5, %33, off offset:272 sc1\n\t" \
    "global_load_dwordx4 %6, %33, off offset:384 sc1\n\t" \
    "global_load_dwordx4 %7, %33, off offset:400 sc1\n\t" \
    "global_load_dwordx4 %8, %33, off offset:512 sc1\n\t" \
    "global_load_dwordx4 %9, %33, off offset:528 sc1\n\t" \
    "global_load_dwordx4 %10, %33, off offset:640 sc1\n\t" \
    "global_load_dwordx4 %11, %33, off offset:656 sc1\n\t" \
    "global_load_dwordx4 %12, %33, off offset:768 sc1\n\t" \
    "global_load_dwordx4 %13, %33, off offset:784 sc1\n\t" \
    "global_load_dwordx4 %14, %33, off offset:896 sc1\n\t" \
    "global_load_dwordx4 %15, %33, off offset:912 sc1\n\t" \
    "global_load_dwordx4 %16, %33, off offset:1024 sc1\n\t" \
    "global_load_dwordx4 %17, %33, off offset:1040 sc1\n\t" \
    "global_load_dwordx4 %18, %33, off offset:1152 sc1\n\t" \
    "global_load_dwordx4 %19, %33, off offset:1168 sc1\n\t" \
    "global_load_dwordx4 %20, %33, off offset:1280 sc1\n\t" \
    "global_load_dwordx4 %21, %33, off offset:1296 sc1\n\t" \
    "global_load_dwordx4 %22, %33, off offset:1408 sc1\n\t" \
    "global_load_dwordx4 %23, %33, off offset:1424 sc1\n\t" \
    "global_load_dwordx4 %24, %33, off offset:1536 sc1\n\t" \
    "global_load_dwordx4 %25, %33, off offset:1552 sc1\n\t" \
    "global_load_dwordx4 %26, %33, off offset:1664 sc1\n\t" \
    "global_load_dwordx4 %27, %33, off offset:1680 sc1\n\t" \
    "global_load_dwordx4 %28, %33, off offset:1792 sc1\n\t" \
    "global_load_dwordx4 %29, %33, off offset:1808 sc1\n\t" \
    "global_load_dwordx4 %30, %33, off offset:1920 sc1\n\t" \
    "global_load_dwordx4 %31, %33, off offset:1936 sc1\n\t" \
    "global_load_dword   %32, %34, off sc1\n\t" \
    "s_waitcnt vmcnt(0)" \
    : "=&v"((W)[0]), "=&v"((W)[1]), "=&v"((W)[2]), "=&v"((W)[3]), \
      "=&v"((W)[4]), "=&v"((W)[5]), "=&v"((W)[6]), "=&v"((W)[7]), \
      "=&v"((W)[8]), "=&v"((W)[9]), "=&v"((W)[10]), "=&v"((W)[11]), \
      "=&v"((W)[12]), "=&v"((W)[13]), "=&v"((W)[14]), "=&v"((W)[15]), \
      "=&v"((W)[16]), "=&v"((W)[17]), "=&v"((W)[18]), "=&v"((W)[19]), \
      "=&v"((W)[20]), "=&v"((W)[21]), "=&v"((W)[22]), "=&v"((W)[23]), \
      "=&v"((W)[24]), "=&v"((W)[25]), "=&v"((W)[26]), "=&v"((W)[27]), \
      "=&v"((W)[28]), "=&v"((W)[29]), "=&v"((W)[30]), "=&v"((W)[31]), \
      "=&v"(PV) \
    : "v"(HB), "v"(PP) \
    : "memory")

// 16x dwordx4 x-loads (8 f32 frags), plain cached, + vmcnt(0)
#define LDX16(W, B) \
  asm volatile( \
    "global_load_dwordx4 %0, %16, off\n\t" \
    "global_load_dwordx4 %1, %16, off offset:16\n\t" \
    "global_load_dwordx4 %2, %16, off offset:128\n\t" \
    "global_load_dwordx4 %3, %16, off offset:144\n\t" \
    "global_load_dwordx4 %4, %16, off offset:256\n\t" \
    "global_load_dwordx4 %5, %16, off offset:272\n\t" \
    "global_load_dwordx4 %6, %16, off offset:384\n\t" \
    "global_load_dwordx4 %7, %16, off offset:400\n\t" \
    "global_load_dwordx4 %8, %16, off offset:512\n\t" \
    "global_load_dwordx4 %9, %16, off offset:528\n\t" \
    "global_load_dwordx4 %10, %16, off offset:640\n\t" \
    "global_load_dwordx4 %11, %16, off offset:656\n\t" \
    "global_load_dwordx4 %12, %16, off offset:768\n\t" \
    "global_load_dwordx4 %13, %16, off offset:784\n\t" \
    "global_load_dwordx4 %14, %16, off offset:896\n\t" \
    "global_load_dwordx4 %15, %16, off offset:912\n\t" \
    "s_waitcnt vmcnt(0)" \
    : "=&v"((W)[0]), "=&v"((W)[1]), "=&v"((W)[2]), "=&v"((W)[3]), \
      "=&v"((W)[4]), "=&v"((W)[5]), "=&v"((W)[6]), "=&v"((W)[7]), \
      "=&v"((W)[8]), "=&v"((W)[9]), "=&v"((W)[10]), "=&v"((W)[11]), \
      "=&v"((W)[12]), "=&v"((W)[13]), "=&v"((W)[14]), "=&v"((W)[15]) \
    : "v"(B) \
    : "memory")

// 16x dwordx4 y-loads (16 f16 frags, row stride 1024B, frag stride 64B) + wait
#define LDY16(W, B) \
  asm volatile( \
    "global_load_dwordx4 %0, %16, off sc1\n\t" \
    "global_load_dwordx4 %1, %16, off offset:64 sc1\n\t" \
    "global_load_dwordx4 %2, %16, off offset:128 sc1\n\t" \
    "global_load_dwordx4 %3, %16, off offset:192 sc1\n\t" \
    "global_load_dwordx4 %4, %16, off offset:256 sc1\n\t" \
    "global_load_dwordx4 %5, %16, off offset:320 sc1\n\t" \
    "global_load_dwordx4 %6, %16, off offset:384 sc1\n\t" \
    "global_load_dwordx4 %7, %16, off offset:448 sc1\n\t" \
    "global_load_dwordx4 %8, %16, off offset:512 sc1\n\t" \
    "global_load_dwordx4 %9, %16, off offset:576 sc1\n\t" \
    "global_load_dwordx4 %10, %16, off offset:640 sc1\n\t" \
    "global_load_dwordx4 %11, %16, off offset:704 sc1\n\t" \
    "global_load_dwordx4 %12, %16, off offset:768 sc1\n\t" \
    "global_load_dwordx4 %13, %16, off offset:832 sc1\n\t" \
    "global_load_dwordx4 %14, %16, off offset:896 sc1\n\t" \
    "global_load_dwordx4 %15, %16, off offset:960 sc1\n\t" \
    "s_waitcnt vmcnt(0)" \
    : "=&v"((W)[0]), "=&v"((W)[1]), "=&v"((W)[2]), "=&v"((W)[3]), \
      "=&v"((W)[4]), "=&v"((W)[5]), "=&v"((W)[6]), "=&v"((W)[7]), \
      "=&v"((W)[8]), "=&v"((W)[9]), "=&v"((W)[10]), "=&v"((W)[11]), \
      "=&v"((W)[12]), "=&v"((W)[13]), "=&v"((W)[14]), "=&v"((W)[15]) \
    : "v"(B) \
    : "memory")

// fire-and-forget sc1 stores (no dest regs -> no pending-load hazard)
__device__ __forceinline__ void st_u1_sc1(unsigned* p, unsigned v) {
    asm volatile("global_store_dword %0, %1, off sc1" :: "v"(p), "v"(v) : "memory");
}
__device__ __forceinline__ void st_h_sc1(_Float16* p, float f) {
    unsigned hv = (unsigned)__builtin_bit_cast(unsigned short, (_Float16)f);
    asm volatile("global_store_short %0, %1, off sc1" :: "v"(p), "v"(hv) : "memory");
}

// watchdog'd flag spin (per-lane pointer; self-contained load+wait)
__device__ __forceinline__ void spin_ge(const unsigned* p, int tgt, bool* dead,
                                        unsigned long long bud) {
    if (*dead) return;
    unsigned long long t0 = clock64();
    for (;;) {
        unsigned v;
        asm volatile("global_load_dword %0, %1, off sc1\n\ts_waitcnt vmcnt(0)"
                     : "=v"(v) : "v"(p) : "memory");
        if (__all((int)v >= tgt)) return;
        if (clock64() - t0 > bud) { *dead = true; return; }
    }
}

__device__ __forceinline__ unsigned vb32(const uint4* w, unsigned etag) {
    unsigned a = 0;
#pragma unroll
    for (int i = 0; i < 32; ++i)
        a |= (w[i].x ^ etag) | (w[i].y ^ etag) | (w[i].z ^ etag) | (w[i].w ^ etag);
    return a >> 16;
}
__device__ __forceinline__ f16x8 packfrag(uint4 lo, uint4 hi) {
    uint4 r;
    r.x = (lo.x & 0xFFFFu) | (lo.y << 16);
    r.y = (lo.z & 0xFFFFu) | (lo.w << 16);
    r.z = (hi.x & 0xFFFFu) | (hi.y << 16);
    r.w = (hi.z & 0xFFFFu) | (hi.w << 16);
    return __builtin_bit_cast(f16x8, r);
}

#define BFRAG(g, kt) __builtin_bit_cast(f16x8, ldsB[((g) * 16 + (kt)) * 64 + lane])
#define WFRAG(g, kt) __builtin_bit_cast(f16x8, ldsWi[((g) * 16 + (kt)) * 64 + lane])

__global__ __launch_bounds__(256, 1) void gru_scan(
    const float* __restrict__ x,     // [64,1024,256]
    const float* __restrict__ Wi0, const float* __restrict__ bi0,
    const float* __restrict__ Wh0, const float* __restrict__ bhn0,
    const float* __restrict__ Wi1, const float* __restrict__ bi1,
    const float* __restrict__ Wh1, const float* __restrict__ bhn1,
    float* __restrict__ c0_out,      // [64,512]
    float* __restrict__ c1_out,      // [64,512]
    _Float16* __restrict__ y0p,      // y slot 0 (out head)
    _Float16* __restrict__ y1p,      // y slot 1 (out head)
    _Float16* __restrict__ y2p,      // y slot 2 (c0 first half)
    unsigned char* __restrict__ ws)
{
    __shared__ uint4 ldsB[48 * 64];   // W_h fragments (48 KB)
    __shared__ uint4 ldsWi[48 * 64];  // W_i fragments (48 KB; L0 uses kt<8)

    const int tid  = threadIdx.x;
    const int wave = tid >> 6;
    const int lane = tid & 63;
    const int quad = lane >> 4;
    const int l16  = lane & 15;
    const int wg   = blockIdx.x;
    const bool isL1 = (wg >= NWG_L0);
    const int rank = isL1 ? (wg - NWG_L0) : wg;
    const int cslice = rank * 16;

    unsigned* yfl  = (unsigned*)(ws + YFLAG_OFF);
    unsigned* prog = (unsigned*)(ws + PROG_OFF);

    const float* Wh = isL1 ? Wh1 : Wh0;
    const float* Wi = isL1 ? Wi1 : Wi0;

    // ---- stage W_h / W_i fragments into LDS ----
    // B-frag (16x16x32): lane holds B[k = kt*32 + quad*8 + j][n = l16]
    for (int f = wave * 12; f < wave * 12 + 12; ++f) {
        int nt = f >> 4, kt = f & 15;
        const float* src = Wh + (kt * 32 + quad * 8) * 1536 + nt * 512 + cslice + l16;
        ldsB[f * 64 + lane] = __builtin_bit_cast(uint4, pack8(src, 1536));
        if (isL1 || kt < 8) {
            const float* si = Wi + (kt * 32 + quad * 8) * 1536 + nt * 512 + cslice + l16;
            ldsWi[f * 64 + lane] = __builtin_bit_cast(uint4, pack8(si, 1536));
        }
    }

    const float* bi = isL1 ? bi1 : bi0;
    const float* bh = isL1 ? bhn1 : bhn0;
    const float bi_r = bi[cslice + l16];
    const float bi_z = bi[512 + cslice + l16];
    const float bi_n = bi[1024 + cslice + l16];
    const float bhn  = bh[cslice + l16];

    __syncthreads();

    float hstate[4] = {0.f, 0.f, 0.f, 0.f};
    const int rowA = wave * 16 + l16;
    const int rowC = wave * 16 + quad * 4;
    const int cu   = cslice + l16;
    const f32x4 z4 = {0.f, 0.f, 0.f, 0.f};
    bool dead = false;

    if (!isL1) {
        // ================================ L0 ================================
        unsigned* h0t = (unsigned*)(ws + H0T_OFF);
        const unsigned* ppML = prog + (lane & 31) * FST;   // license poll
        unsigned* myyfl = yfl + rank * FST;
        float c0st[4] = {0.f, 0.f, 0.f, 0.f};

        for (int s = 0; s < T_STEPS; ++s) {
            // X block: x(s); internal vmcnt(0) also drains last step's stores
            uint4 xw[16];
            const float* xb = x + (size_t)rowA * 262144 + (size_t)s * 256 + quad * 8;
            LDX16(xw, xb);

            // x-side MFMAs (regs + LDS only; ages our h stores further)
            f32x4 ax0 = z4, ax1 = z4, ax2 = z4;
#pragma unroll
            for (int kt = 0; kt < 8; ++kt) {
                f32x4 x0 = __builtin_bit_cast(f32x4, xw[2 * kt]);
                f32x4 x1 = __builtin_bit_cast(f32x4, xw[2 * kt + 1]);
                f16x8 a;
                a[0] = (_Float16)x0[0]; a[1] = (_Float16)x0[1];
                a[2] = (_Float16)x0[2]; a[3] = (_Float16)x0[3];
                a[4] = (_Float16)x1[0]; a[5] = (_Float16)x1[1];
                a[6] = (_Float16)x1[2]; a[7] = (_Float16)x1[3];
                ax0 = mfma16(a, WFRAG(0, kt), ax0);
                ax1 = mfma16(a, WFRAG(1, kt), ax1);
                ax2 = mfma16(a, WFRAG(2, kt), ax2);
            }

            // H block: 16 tagged frags of h0(s) + prog license word
            const unsigned etag = (unsigned)s << 16;
            const unsigned* hbR = h0t + (unsigned)(s & 1) * 32768u + rowA * 512 + quad * 8;
            uint4 w[32]; unsigned pv;
            LDH33(w, pv, hbR, ppML);

            // publish yfl=s: y(s) stores (issued at iter s-1 end) were drained
            // by this wave's LDX16/LDH33 vmcnt(0); syncthreads covers all waves
            __syncthreads();
            if (tid == 0) st_u1_sc1(myyfl, (unsigned)s);

            // validate tags; bounded retry (self/peer stores still in flight)
            unsigned bad = vb32(w, etag);
            if (__any((int)(bad != 0u)) && !dead) {
                unsigned long long t0 = clock64();
                while (__any((int)(bad != 0u))) {
                    LDH33(w, pv, hbR, ppML);
                    bad = vb32(w, etag);
                    if (clock64() - t0 > BUD_SPIN) { dead = true; break; }
                }
            }

            // h-side MFMAs
            f32x4 ah0 = z4, ah1 = z4, ah2 = z4;
#pragma unroll
            for (int kt = 0; kt < 16; ++kt) {
                f16x8 a = packfrag(w[2 * kt], w[2 * kt + 1]);
                ah0 = mfma16(a, BFRAG(0, kt), ah0);
                ah1 = mfma16(a, BFRAG(1, kt), ah1);
                ah2 = mfma16(a, BFRAG(2, kt), ah2);
            }

            float hnv[4], ytv[4];
#pragma unroll
            for (int i = 0; i < 4; ++i) {
                float r  = sigm_f(ax0[i] + bi_r + ah0[i]);
                float zz = sigm_f(ax1[i] + bi_z + ah1[i]);
                float n  = tanh_f(ax2[i] + bi_n + r * (ah2[i] + bhn));
                float hnew = (1.0f - zz) * n + zz * hstate[i];
                hstate[i] = hnew; hnv[i] = hnew; ytv[i] = tanh_f(hnew);
            }

            // y-slot reuse license: y(s+1) overwrites y(s-2)
            if (s >= 2 && !__all((int)pv >= s - 2))
                spin_ge(ppML, s - 2, &dead, BUD_SPIN);

            unsigned* hw = h0t + (unsigned)((s + 1) & 1) * 32768u;
            const unsigned wtag = (unsigned)(s + 1) << 16;
            const int sl = (s + 1) % 3;
            _Float16* yw = (sl == 0) ? y0p : ((sl == 1) ? y1p : y2p);
#pragma unroll
            for (int i = 0; i < 4; ++i) {
                unsigned hb16 = (unsigned)__builtin_bit_cast(unsigned short, (_Float16)hnv[i]);
                st_u1_sc1(hw + (rowC + i) * 512 + cu, wtag | hb16);
                st_h_sc1(yw + (rowC + i) * 512 + cu, ytv[i]);
            }
            if (s == T_STEPS - 1) {
#pragma unroll
                for (int i = 0; i < 4; ++i) c0st[i] = hnv[i];
            }
        }

        // epilogue: drain y(1024), publish final yfl, then c0 (y slot 2 region)
        asm volatile("s_waitcnt vmcnt(0)" ::: "memory");
        __syncthreads();
        if (tid == 0) st_u1_sc1(myyfl, (unsigned)T_STEPS);
        spin_ge(ppML, 1022, &dead, BUD_EPI);
#pragma unroll
        for (int i = 0; i < 4; ++i)
            c0_out[(rowC + i) * 512 + cu] = c0st[i];

    } else {
        // ================================ L1 ================================
        unsigned* h1t = (unsigned*)(ws + H1T_OFF);
        const unsigned* ppYF = yfl + (lane & 31) * FST;
        unsigned* myprog = prog + rank * FST;

        for (int s = 1; s <= T_STEPS; ++s) {
            // H block: h1(s-1) tagged + yfl word
            const unsigned etag = (unsigned)(s - 1) << 16;
            const unsigned* hbR = h1t + (unsigned)((s - 1) & 1) * 32768u + rowA * 512 + quad * 8;
            uint4 w[32]; unsigned yv;
            LDH33(w, yv, hbR, ppYF);

            // y license MUST be observed before y loads are issued
            if (!__all((int)yv >= s))
                spin_ge(ppYF, s, &dead, BUD_SPIN);

            // Y block: y(s) frags (slot s%3)
            const int sl = s % 3;
            const _Float16* yb_ = ((sl == 0) ? y0p : ((sl == 1) ? y1p : y2p))
                                  + rowA * 512 + quad * 8;
            uint4 yw16[16];
            LDY16(yw16, yb_);

            // y-side MFMAs first (frees yw16; ages our h1 stores)
            f32x4 ax0 = z4, ax1 = z4, ax2 = z4;
#pragma unroll
            for (int kt = 0; kt < 16; ++kt) {
                f16x8 ay = __builtin_bit_cast(f16x8, yw16[kt]);
                ax0 = mfma16(ay, WFRAG(0, kt), ax0);
                ax1 = mfma16(ay, WFRAG(1, kt), ax1);
                ax2 = mfma16(ay, WFRAG(2, kt), ax2);
            }

            // validate h tags; bounded retry
            unsigned bad = vb32(w, etag);
            if (__any((int)(bad != 0u)) && !dead) {
                unsigned long long t0 = clock64();
                while (__any((int)(bad != 0u))) {
                    LDH33(w, yv, hbR, ppYF);
                    bad = vb32(w, etag);
                    if (clock64() - t0 > BUD_SPIN) { dead = true; break; }
                }
            }

            f32x4 ah0 = z4, ah1 = z4, ah2 = z4;
#pragma unroll
            for (int kt = 0; kt < 16; ++kt) {
                f16x8 a = packfrag(w[2 * kt], w[2 * kt + 1]);
                ah0 = mfma16(a, BFRAG(0, kt), ah0);
                ah1 = mfma16(a, BFRAG(1, kt), ah1);
                ah2 = mfma16(a, BFRAG(2, kt), ah2);
            }

            float hnv[4];
#pragma unroll
            for (int i = 0; i < 4; ++i) {
                float r  = sigm_f(ax0[i] + bi_r + ah0[i]);
                float zz = sigm_f(ax1[i] + bi_z + ah1[i]);
                float n  = tanh_f(ax2[i] + bi_n + r * (ah2[i] + bhn));
                float hnew = (1.0f - zz) * n + zz * hstate[i];
                hstate[i] = hnew; hnv[i] = hnew;
            }

            unsigned* hw = h1t + (unsigned)(s & 1) * 32768u;
            const unsigned wtag = (unsigned)s << 16;
#pragma unroll
            for (int i = 0; i < 4; ++i) {
                unsigned hb16 = (unsigned)__builtin_bit_cast(unsigned short, (_Float16)hnv[i]);
                st_u1_sc1(hw + (rowC + i) * 512 + cu, wtag | hb16);
                if (s == T_STEPS) c1_out[(rowC + i) * 512 + cu] = hnv[i];
            }

            // prog=s: this wg finished reading y(s) (reads done at LDY16 wait;
            // syncthreads covers all waves)
            __syncthreads();
            if (tid == 0) st_u1_sc1(myprog, (unsigned)s);
        }
    }
}

// out = tanh(tanh(c1) @ W_out + b_out) : [64,512] @ [512,512], fp32
__global__ __launch_bounds__(256) void dense_out(
    const float* __restrict__ c1, const float* __restrict__ Wout,
    const float* __restrict__ bout, float* __restrict__ out)
{
    __shared__ float a[512];
    const int b = blockIdx.x, tid = threadIdx.x;
    a[tid]       = tanh_f(c1[b * 512 + tid]);
    a[tid + 256] = tanh_f(c1[b * 512 + tid + 256]);
    __syncthreads();
    float acc0 = 0.f, acc1 = 0.f;
#pragma unroll 4
    for (int k = 0; k < 512; ++k) {
        const float av = a[k];
        acc0 += av * Wout[k * 512 + tid];
        acc1 += av * Wout[k * 512 + tid + 256];
    }
    out[b * 512 + tid]       = tanh_f(acc0 + bout[tid]);
    out[b * 512 + tid + 256] = tanh_f(acc1 + bout[tid + 256]);
}

extern "C" void kernel_launch(void* const* d_in, const int* in_sizes, int n_in,
                              void* d_out, int out_size, void* d_ws, size_t ws_size,
                              hipStream_t stream)
{
    const float* x    = (const float*)d_in[0];
    const float* Wi0  = (const float*)d_in[1];
    const float* bi0  = (const float*)d_in[2];
    const float* Wh0  = (const float*)d_in[3];
    const float* bhn0 = (const float*)d_in[4];
    const float* Wi1  = (const float*)d_in[5];
    const float* bi1  = (const float*)d_in[6];
    const float* Wh1  = (const float*)d_in[7];
    const float* bhn1 = (const float*)d_in[8];
    const float* Wout = (const float*)d_in[9];
    const float* bout = (const float*)d_in[10];
    float* out = (float*)d_out;
    unsigned char* ws = (unsigned char*)d_ws;

    float* c0 = out + 32768;
    float* c1 = out + 65536;
    _Float16* y0p = (_Float16*)out;          // y slot 0 (out head, 64KB)
    _Float16* y1p = y0p + 32768;             // y slot 1 (out head, 64KB)
    _Float16* y2p = (_Float16*)c0;           // y slot 2 (c0 first half)

    // zero tagged h buffers (tag0|h=0 is the valid initial state) + flags
    hipMemsetAsync(ws, 0, WS_NEED, stream);

    gru_scan<<<NWG_TOT, 256, 0, stream>>>(x, Wi0, bi0, Wh0, bhn0,
                                          Wi1, bi1, Wh1, bhn1,
                                          c0, c1, y0p, y1p, y2p, ws);
    dense_out<<<64, 256, 0, stream>>>(c1, Wout, bout, out);
}